// Round 16
// baseline (328.375 us; speedup 1.0000x reference)
//
#include <hip/hip_runtime.h>
#include <hip/hip_bf16.h>
#include <float.h>

#define PI_D 3.14159265358979323846

// ---------------- problem constants ----------------
#define LWAV 240000
#define TFR  751             // frames per batch
#define BATCH 16
#define MROWS (BATCH * TFR)  // 12016
#define NMEL 128
#define TFRP 753             // frames + 2 halo cols per batch
#define PITCH2 12160         // 95*128 padded m' width
#define MTILES 95
#define MAXW 40

// B-tile LDS column swizzle (f32 conv1)
#define BSWZ(c) ((c) ^ ((((c) >> 5) & 3) << 2))

// ---------------- workspace layout (bytes) ----------------
#define OFF_WIN    0u
#define OFF_TW512  4096u
#define OFF_UTW    8192u
#define OFF_C2MX   12304u        // 4 f32
#define OFF_CNT    12352u        // 1 u32
#define OFF_MELW   16384u        // 128*40*4
#define OFF_MELSL  36864u
#define OFF_WB1    40960u        // 384*256*4 = 393216 -> ends 434176
#define OFF_WBH2   434176u       // 512*768*2 = 786432 (bf16-hi of w2, [n][k])
#define OFF_WBL2   1220608u      // 786432 -> ends 2007040
#define OFF_PB     434176u       //   overlay after conv2m: 8*12160*16 = 1556480 (ends 1990656)
#define OFF_C2     2007040u      // 4*1024*4
#define OFF_CBH    2023424u      // 4096*128*2 = 1048576
#define OFF_CBL    3072000u      // -> ends 4120576
#define OFF_X2     4120576u      // 4*12160*4 -> ends 4315136
#define OFF_HT     4317184u      // 256*12160*4 = 12451840 (ALIVE through vqfix)
#define OFF_FET    16777216u     // 512*12160*4 = 24903680 -> ends 41680896
#define OFF_LMT    OFF_FET       //   overlay (lmT dead before conv2m writes feT)
// post-vqmfma overlays inside the dead feT region:
#define OFF_LIST   OFF_FET                  // 48064*4 = 192256
#define OFF_WT2F   (OFF_FET + 262144u)      // 768*512*4 = 1572864 -> ends 18612224
#define OFF_CBTF   18612224u                // 4*128*1024*4 = 2097152 -> ends 20709376
#define WS_NEEDED  41685000u

typedef unsigned short u16;
typedef __attribute__((ext_vector_type(8))) __bf16 bf16x8;
typedef __attribute__((ext_vector_type(4))) float f32x4;
union UB { uint4 u; bf16x8 v; };
union UA { u16 s[8]; bf16x8 v; };

__device__ __forceinline__ u16 bf16rne(float x) {
  unsigned u = __float_as_uint(x);
  return (u16)((u + 0x7FFFu + ((u >> 16) & 1u)) >> 16);
}
__device__ __forceinline__ float bf16tof(u16 h) {
  return __uint_as_float(((unsigned)h) << 16);
}

// XCD-aware job remap: grid is 1-D with G = 8*GP blocks. Jobs that share an
// A-tile are CONSECUTIVE job ids; this mapping gives each XCD (bid%8) a
// contiguous job chunk -> sharers land on one XCD's L2.
__device__ __forceinline__ int jobmap(int bid, int GP) {
  return (bid & 7) * GP + (bid >> 3);
}

// ---------------- setup kernels ----------------
__global__ void k_setup_tab(float* __restrict__ win, float2* __restrict__ tw512,
                            float2* __restrict__ utw) {
  int t = threadIdx.x;
  if (t < 1024) {
    double v = 0.5 * (1.0 - cos(2.0 * PI_D * (double)t / 1024.0));
    win[t] = (float)v;
  }
  if (t < 512) {
    double a = -2.0 * PI_D * (double)t / 512.0;
    tw512[t] = make_float2((float)cos(a), (float)sin(a));
  }
  if (t < 513) {
    double a = -2.0 * PI_D * (double)t / 1024.0;
    utw[t] = make_float2((float)cos(a), (float)sin(a));
  }
}

__device__ __forceinline__ double fpt_d(int j) {
  double melmax = 2595.0 * log10(1.0 + 12000.0 / 700.0);
  double mp = melmax * (double)j / 129.0;
  return 700.0 * (pow(10.0, mp / 2595.0) - 1.0);
}

__global__ void k_melw(float* __restrict__ melw, int2* __restrict__ melsl) {
  int m = threadIdx.x;
  double f0 = fpt_d(m), f1 = fpt_d(m + 1), f2 = fpt_d(m + 2);
  const double binw = 12000.0 / 512.0;
  int s = (int)floor(f0 / binw) + 1;
  if (s < 0) s = 0;
  int e = (int)ceil(f2 / binw) - 1;
  if (e > 512) e = 512;
  int len = e - s + 1;
  if (len < 0) len = 0;
  if (len > MAXW) len = MAXW;
  melsl[m] = make_int2(s, len);
  for (int j = 0; j < MAXW; ++j) {
    double freq = binw * (double)(s + j);
    double down = (freq - f0) / (f1 - f0);
    double up = (f2 - freq) / (f2 - f1);
    double v = fmin(down, up);
    v = fmax(0.0, v);
    melw[m * MAXW + j] = (j < len) ? (float)v : 0.f;
  }
}

// conv1 weights (f32): wt[(dt*C+i)*O + o] = w[(o*C+i)*3 + dt]
__global__ void k_wt(const float* __restrict__ w, float* __restrict__ wt,
                     int O, int C) {
  int idx = blockIdx.x * 256 + threadIdx.x;
  int total = O * C * 3;
  if (idx >= total) return;
  int o = idx % O;
  int rest = idx / O;
  int i = rest % C;
  int dt = rest / C;
  wt[(dt * C + i) * O + o] = w[(o * C + i) * 3 + dt];
}

// conv2 weights: bf16 hi/lo split, layout [o][k] with k = dt*256 + i
__global__ void k_wt2conv(const float* __restrict__ w2, u16* __restrict__ wbH2,
                          u16* __restrict__ wbL2) {
  int idx = blockIdx.x * 256 + threadIdx.x;  // 512*768 = 393216
  if (idx >= 512 * 768) return;
  int o = idx / 768;
  int k = idx - o * 768;
  int dt = k >> 8, i = k & 255;
  float x = w2[(size_t)(o * 256 + i) * 3 + dt];
  u16 hh = bf16rne(x);
  wbH2[idx] = hh;
  wbL2[idx] = bf16rne(x - bf16tof(hh));
}

// f32 transposed conv2 weights: wt2f[k*512 + o] = w2[o][k], k = dt*256+i
__global__ void k_wt2f(const float* __restrict__ w2, float* __restrict__ wt2f) {
  int idx = blockIdx.x * 256 + threadIdx.x;  // 393216
  if (idx >= 768 * 512) return;
  int o = idx & 511, k = idx >> 9;
  int dt = k >> 8, i = k & 255;
  wt2f[idx] = w2[(size_t)(o * 256 + i) * 3 + dt];
}

// f32 transposed codebooks: cbTf[(cb*128+d)*1024 + v] = cbs[(cb*1024+v)*128 + d]
__global__ void k_cbtf(const float* __restrict__ cbs, float* __restrict__ cbTf) {
  int idx = blockIdx.x * 256 + threadIdx.x;  // 524288
  int v = idx & 1023;
  int d = (idx >> 10) & 127;
  int cb = idx >> 17;
  cbTf[idx] = cbs[(size_t)((cb << 10) + v) * 128 + d];
}

__global__ void k_c2(const float* __restrict__ cb, float* __restrict__ c2) {
  int v = blockIdx.x * 256 + threadIdx.x;
  if (v >= 4096) return;
  const float* r = cb + (size_t)v * 128;
  float s = 0.f;
#pragma unroll 8
  for (int i = 0; i < 128; ++i) s = fmaf(r[i], r[i], s);
  c2[v] = s;
}

__global__ void k_c2mx(const float* __restrict__ c2, float* __restrict__ c2mx,
                       unsigned* __restrict__ cnt) {
  __shared__ float red[256];
  int cb = blockIdx.x, tid = threadIdx.x;
  float m = 0.f;
  for (int v = tid; v < 1024; v += 256) m = fmaxf(m, c2[cb * 1024 + v]);
  red[tid] = m;
  __syncthreads();
  for (int s = 128; s > 0; s >>= 1) {
    if (tid < s) red[tid] = fmaxf(red[tid], red[tid + s]);
    __syncthreads();
  }
  if (tid == 0) {
    c2mx[cb] = red[0];
    if (cb == 0) *cnt = 0u;
  }
}

__global__ void k_cbconv(const float* __restrict__ cbs, u16* __restrict__ cbH,
                         u16* __restrict__ cbL) {
  int id = blockIdx.x * 256 + threadIdx.x;  // 131072
  int v = id >> 5, d4 = (id & 31) * 4;
  float4 x = *(const float4*)(cbs + (size_t)v * 128 + d4);
  const float xs[4] = {x.x, x.y, x.z, x.w};
  unsigned wh[2], wl[2];
#pragma unroll
  for (int p = 0; p < 2; ++p) {
    u16 h0 = bf16rne(xs[2 * p]);
    u16 h1 = bf16rne(xs[2 * p + 1]);
    u16 l0 = bf16rne(xs[2 * p] - bf16tof(h0));
    u16 l1 = bf16rne(xs[2 * p + 1] - bf16tof(h1));
    wh[p] = (unsigned)h0 | ((unsigned)h1 << 16);
    wl[p] = (unsigned)l0 | ((unsigned)l1 << 16);
  }
  *(uint2*)(cbH + (size_t)v * 128 + d4) = make_uint2(wh[0], wh[1]);
  *(uint2*)(cbL + (size_t)v * 128 + d4) = make_uint2(wl[0], wl[1]);
}

__global__ void k_zerocols(float* __restrict__ a, int rows) {
  int tid = blockIdx.x * 256 + threadIdx.x;
  int col_id = tid & 31;
  int r = tid >> 5;
  if (r >= rows) return;
  int bq = col_id >> 1;
  int c = bq * TFRP + ((col_id & 1) ? 752 : 0);
  a[(size_t)r * PITCH2 + c] = 0.f;
}

// ---------------- complex helpers / radix-8 DFT ----------------
__device__ __forceinline__ float2 cadd(float2 a, float2 b) { return make_float2(a.x + b.x, a.y + b.y); }
__device__ __forceinline__ float2 csub(float2 a, float2 b) { return make_float2(a.x - b.x, a.y - b.y); }
__device__ __forceinline__ float2 cmul(float2 a, float2 b) {
  return make_float2(a.x * b.x - a.y * b.y, a.x * b.y + a.y * b.x);
}
__device__ __forceinline__ float2 mulnegi(float2 a) { return make_float2(a.y, -a.x); }

__device__ __forceinline__ void dft8(const float2* d, float2* o) {
  const float S = 0.70710678118654752440f;
  float2 f0 = cadd(d[0], d[4]), f1 = csub(d[0], d[4]);
  float2 f2 = cadd(d[2], d[6]), f3 = csub(d[2], d[6]);
  float2 h0 = cadd(d[1], d[5]), h1 = csub(d[1], d[5]);
  float2 h2 = cadd(d[3], d[7]), h3 = csub(d[3], d[7]);
  float2 E0 = cadd(f0, f2), E2 = csub(f0, f2);
  float2 nif3 = mulnegi(f3);
  float2 E1 = cadd(f1, nif3), E3 = csub(f1, nif3);
  float2 O0 = cadd(h0, h2), O2 = csub(h0, h2);
  float2 nih3 = mulnegi(h3);
  float2 O1 = cadd(h1, nih3), O3 = csub(h1, nih3);
  float2 w1o = make_float2(S * (O1.x + O1.y), S * (O1.y - O1.x));
  float2 w2o = mulnegi(O2);
  float2 w3o = make_float2(S * (O3.y - O3.x), -S * (O3.x + O3.y));
  o[0] = cadd(E0, O0);  o[4] = csub(E0, O0);
  o[1] = cadd(E1, w1o); o[5] = csub(E1, w1o);
  o[2] = cadd(E2, w2o); o[6] = csub(E2, w2o);
  o[3] = cadd(E3, w3o); o[7] = csub(E3, w3o);
}

__device__ __forceinline__ float powspec(const float2* Z, const float2* __restrict__ utw,
                                         int k) {
  float2 Zk = Z[k & 511];
  float2 Zm = Z[(512 - k) & 511];
  float2 ut = utw[k];
  float fer = 0.5f * (Zk.x + Zm.x);
  float fei = 0.5f * (Zk.y - Zm.y);
  float fo_r = 0.5f * (Zk.y + Zm.y);
  float fo_i = -0.5f * (Zk.x - Zm.x);
  float xr = fer + ut.x * fo_r - ut.y * fo_i;
  float xi = fei + ut.x * fo_i + ut.y * fo_r;
  return xr * xr + xi * xi;
}

// ---------------- log-mel ----------------
__global__ __launch_bounds__(256) void k_logmel3(
    const float* __restrict__ wav, const float* __restrict__ win,
    const float2* __restrict__ tw512, const float2* __restrict__ utw,
    const float* __restrict__ melw, const int2* __restrict__ melsl,
    float* __restrict__ lmT) {
  __shared__ float2 zbuf[4][512];
  __shared__ float pbuf[4][516];
  __shared__ float mex[128][5];

  const int w = threadIdx.x >> 6;
  const int t = threadIdx.x & 63;
  const int bq = blockIdx.x / 188;
  const int t0 = (blockIdx.x % 188) * 4;
  const int tt = min(t0 + w, TFR - 1);
  const float* wv = wav + (size_t)bq * LWAV;
  float2* Z = zbuf[w];
  float* p = pbuf[w];

  const int base = tt * 320 - 512;

  float2 c[8];
  if (base >= 0 && base + 1024 <= LWAV) {
    const float2* wv2 = (const float2*)(wv + base);
    const float2* wn2 = (const float2*)win;
#pragma unroll
    for (int j = 0; j < 8; ++j) {
      int mm = t + 64 * j;
      float2 xv = wv2[mm];
      float2 wn = wn2[mm];
      c[j] = make_float2(xv.x * wn.x, xv.y * wn.y);
    }
  } else {
#pragma unroll
    for (int j = 0; j < 8; ++j) {
      int mm = t + 64 * j;
      int n0 = base + 2 * mm, n1 = n0 + 1;
      int j0 = n0 < 0 ? -n0 : (n0 >= LWAV ? 2 * LWAV - 2 - n0 : n0);
      int j1 = n1 < 0 ? -n1 : (n1 >= LWAV ? 2 * LWAV - 2 - n1 : n1);
      c[j] = make_float2(wv[j0] * win[2 * mm], wv[j1] * win[2 * mm + 1]);
    }
  }

  float2 e[8];
  dft8(c, e);
#pragma unroll
  for (int pp = 1; pp < 8; ++pp) e[pp] = cmul(e[pp], tw512[(t * pp) & 511]);
#pragma unroll
  for (int pp = 0; pp < 8; ++pp) Z[pp * 64 + (t ^ (pp << 3))] = e[pp];
  asm volatile("s_waitcnt lgkmcnt(0)" ::: "memory");

  const int P = t >> 3, M = t & 7;
  float2 g[8];
#pragma unroll
  for (int v = 0; v < 8; ++v) g[v] = Z[P * 64 + ((M + 8 * v) ^ (P << 3))];
  asm volatile("s_waitcnt lgkmcnt(0)" ::: "memory");

  float2 y[8];
  dft8(g, y);
#pragma unroll
  for (int aa = 1; aa < 8; ++aa) y[aa] = cmul(y[aa], tw512[(8 * M * aa) & 511]);
#pragma unroll
  for (int aa = 0; aa < 8; ++aa) Z[aa * 64 + (((M << 3) + P) ^ (aa << 3))] = y[aa];
  asm volatile("s_waitcnt lgkmcnt(0)" ::: "memory");

  float2 yv[8];
#pragma unroll
  for (int u = 0; u < 8; ++u) yv[u] = Z[P * 64 + (((u << 3) + M) ^ (P << 3))];
  asm volatile("s_waitcnt lgkmcnt(0)" ::: "memory");

  float2 X[8];
  dft8(yv, X);
#pragma unroll
  for (int bb = 0; bb < 8; ++bb) Z[bb * 64 + t] = X[bb];
  asm volatile("s_waitcnt lgkmcnt(0)" ::: "memory");

#pragma unroll
  for (int j = 0; j < 8; ++j) {
    int k = t + 64 * j;
    p[k] = powspec(Z, utw, k);
  }
  if (t == 0) p[512] = powspec(Z, utw, 512);
  asm volatile("s_waitcnt lgkmcnt(0)" ::: "memory");

#pragma unroll
  for (int h = 0; h < 2; ++h) {
    int m = 2 * t + h;
    int2 sl = melsl[m];
    float acc = 0.f;
    const float* wrow = melw + m * MAXW;
    for (int j = 0; j < sl.y; ++j) acc = fmaf(p[sl.x + j], wrow[j], acc);
    mex[m][w] = logf(fmaxf(acc, 1e-5f));
  }
  __syncthreads();
  if (threadIdx.x < 128) {
    int cc = threadIdx.x;
    float* op = lmT + (size_t)cc * PITCH2 + (size_t)bq * TFRP + 1 + t0;
    op[0] = mex[cc][0];
    op[1] = mex[cc][1];
    op[2] = mex[cc][2];
    op[3] = mex[cc][3];
  }
}

// ---------------- conv1: f32 64m x 64n GEMM, XCD-swizzled 1-D grid (760) ---------
template <int C, int N, int BN, bool GELU>
__global__ __launch_bounds__(256) void k_conv64(const float* __restrict__ in,
                                                const float* __restrict__ wt,
                                                const float* __restrict__ bias,
                                                float* __restrict__ out) {
  constexpr int K = 3 * C;
  constexpr int NC = BN / 16;
  __shared__ float At[32 * 64];
  __shared__ float Bt[32 * BN];
  const int j = jobmap(blockIdx.x, 95);   // 760 jobs: mt = j>>2, nb = j&3
  const int m0 = (j >> 2) * 64;
  const int n0 = (j & 3) * BN;
  const int tid = threadIdx.x;
  const int tm = tid >> 4, tn = tid & 15;

  int bco[NC / 4];
#pragma unroll
  for (int i = 0; i < NC / 4; ++i) bco[i] = BSWZ(tn * NC + i * 4);

  float acc[4][NC] = {};

  for (int k0 = 0; k0 < K; k0 += 32) {
    const int dt = k0 / C;
    const int i0 = k0 - dt * C;
    const float* asrc = in + (size_t)i0 * PITCH2 + (m0 + dt - 1);
    const float* bsrc = wt + (size_t)k0 * N + n0;
#pragma unroll
    for (int h = 0; h < 2; ++h) {
      const int id = tid + h * 256;
      const int r = id >> 4, cf = (id & 15) * 4;
      const float* ap = asrc + (size_t)r * PITCH2 + cf;
      *(float4*)&At[r * 64 + cf] = make_float4(ap[0], ap[1], ap[2], ap[3]);
    }
#pragma unroll
    for (int h = 0; h < BN / 32; ++h) {
      const int id = tid + h * 256;
      const int r = id / (BN / 4), cf = (id % (BN / 4)) * 4;
      *(float4*)&Bt[r * BN + BSWZ(cf)] = *(const float4*)(bsrc + (size_t)r * N + cf);
    }
    __syncthreads();
#pragma unroll
    for (int kc = 0; kc < 32; ++kc) {
      float4 a = *(const float4*)&At[kc * 64 + tm * 4];
      float av[4] = {a.x, a.y, a.z, a.w};
      float bv[NC];
#pragma unroll
      for (int i = 0; i < NC / 4; ++i) {
        float4 b = *(const float4*)&Bt[kc * BN + bco[i]];
        bv[i * 4] = b.x; bv[i * 4 + 1] = b.y; bv[i * 4 + 2] = b.z; bv[i * 4 + 3] = b.w;
      }
#pragma unroll
      for (int r = 0; r < 4; ++r)
#pragma unroll
        for (int cq = 0; cq < NC; ++cq) acc[r][cq] = fmaf(av[r], bv[cq], acc[r][cq]);
    }
    __syncthreads();
  }

#pragma unroll
  for (int cq = 0; cq < NC; ++cq) {
    const int n = n0 + tn * NC + cq;
    const float bb = bias[n];
    float vv[4];
#pragma unroll
    for (int r = 0; r < 4; ++r) {
      float v = acc[r][cq] + bb;
      if (GELU) v = 0.5f * v * (1.0f + erff(v * 0.7071067811865476f));
      vv[r] = v;
    }
    *(float4*)(out + (size_t)n * PITCH2 + m0 + tm * 4) =
        make_float4(vv[0], vv[1], vv[2], vv[3]);
  }
}

// ---------------- conv2 via split-bf16 MFMA, dbuf+prefetch, XCD-swizzled ---------
#define MFMA16(a, b, c) __builtin_amdgcn_mfma_f32_16x16x32_bf16((a), (b), (c), 0, 0, 0)

#define C2M_ISSUE_A(dst, cc) do {                                           \
    const int kc0_ = (cc) * 32;                                             \
    const int dt_ = kc0_ >> 8, i0_ = kc0_ & 255;                            \
    const float* hb_ = hT + (size_t)(i0_ + g * 8) * PITCH2                  \
                       + m0 + mhalf * 32 + ln + dt_ - 1;                    \
    _Pragma("unroll") for (int mi_ = 0; mi_ < 2; ++mi_)                     \
      _Pragma("unroll") for (int j_ = 0; j_ < 8; ++j_)                      \
        dst[mi_][j_] = hb_[(size_t)j_ * PITCH2 + mi_ * 16];                 \
  } while (0)

#define C2M_ISSUE_B(cc) do {                                                \
    const int kc0_ = (cc) * 32;                                             \
    _Pragma("unroll") for (int h2_ = 0; h2_ < 2; ++h2_) {                   \
      const int id_ = tid + h2_ * 256;                                      \
      const int nn_ = id_ >> 2, part_ = id_ & 3;                            \
      const size_t src_ = (size_t)(n0 + nn_) * 768 + kc0_ + part_ * 8;      \
      rBh[h2_] = *(const uint4*)(wbH2 + src_);                              \
      rBl[h2_] = *(const uint4*)(wbL2 + src_);                              \
    }                                                                       \
  } while (0)

#define C2M_COMMIT_B(buf) do {                                              \
    _Pragma("unroll") for (int h2_ = 0; h2_ < 2; ++h2_) {                   \
      const int id_ = tid + h2_ * 256;                                      \
      const int nn_ = id_ >> 2, part_ = id_ & 3;                            \
      *(uint4*)&bHs[buf][nn_ * 40 + part_ * 8] = rBh[h2_];                  \
      *(uint4*)&bLs[buf][nn_ * 40 + part_ * 8] = rBl[h2_];                  \
    }                                                                       \
  } while (0)

__global__ __launch_bounds__(256) void k_conv2m(
    const float* __restrict__ hT,
    const u16* __restrict__ wbH2, const u16* __restrict__ wbL2,
    const float* __restrict__ b2, float* __restrict__ feT) {
  __shared__ __align__(16) u16 bHs[2][128 * 40];  // [buf][n][32k + 8 pad]
  __shared__ __align__(16) u16 bLs[2][128 * 40];
  const int j = jobmap(blockIdx.x, 95);   // 760 jobs: mt = j>>2, nq = j&3
  const int mt = j >> 2;
  const int nq = j & 3;
  const int tid = threadIdx.x;
  const int w = tid >> 6, l = tid & 63;
  const int mhalf = w & 1, nhalf = w >> 1;
  const int g = l >> 4, ln = l & 15;
  const int m0 = mt * 64;
  const int n0 = nq * 128;

  f32x4 acc[2][4];
#pragma unroll
  for (int mi = 0; mi < 2; ++mi)
#pragma unroll
    for (int vi = 0; vi < 4; ++vi) acc[mi][vi] = (f32x4){0.f, 0.f, 0.f, 0.f};

  float rA[2][8], rA2[2][8];
  uint4 rBh[2], rBl[2];

  C2M_ISSUE_A(rA, 0);
  C2M_ISSUE_B(0);
  C2M_COMMIT_B(0);
  __syncthreads();

  int cur = 0;
  for (int cc = 0; cc < 24; ++cc) {
    const bool more = (cc + 1 < 24);
    if (more) { C2M_ISSUE_B(cc + 1); C2M_ISSUE_A(rA2, cc + 1); }
    UA aH[2], aL[2];
#pragma unroll
    for (int mi = 0; mi < 2; ++mi)
#pragma unroll
      for (int jx = 0; jx < 8; ++jx) {
        u16 hh = bf16rne(rA[mi][jx]);
        aH[mi].s[jx] = hh;
        aL[mi].s[jx] = bf16rne(rA[mi][jx] - bf16tof(hh));
      }
    const u16* bH = bHs[cur];
    const u16* bL = bLs[cur];
    __builtin_amdgcn_s_setprio(1);
#pragma unroll
    for (int vi = 0; vi < 4; ++vi) {
      const int nn = nhalf * 64 + vi * 16 + ln;
      UB bh, bl;
      bh.u = *(const uint4*)&bH[nn * 40 + g * 8];
      bl.u = *(const uint4*)&bL[nn * 40 + g * 8];
#pragma unroll
      for (int mi = 0; mi < 2; ++mi) {
        acc[mi][vi] = MFMA16(aH[mi].v, bh.v, acc[mi][vi]);
        acc[mi][vi] = MFMA16(aH[mi].v, bl.v, acc[mi][vi]);
        acc[mi][vi] = MFMA16(aL[mi].v, bh.v, acc[mi][vi]);
      }
    }
    __builtin_amdgcn_s_setprio(0);
    if (more) {
      C2M_COMMIT_B(cur ^ 1);
      __syncthreads();
      cur ^= 1;
#pragma unroll
      for (int mi = 0; mi < 2; ++mi)
#pragma unroll
        for (int jx = 0; jx < 8; ++jx) rA[mi][jx] = rA2[mi][jx];
    }
  }

#pragma unroll
  for (int vi = 0; vi < 4; ++vi) {
    const int nn = n0 + nhalf * 64 + vi * 16 + ln;
    const float bb = b2[nn];
#pragma unroll
    for (int mi = 0; mi < 2; ++mi) {
      f32x4 A = acc[mi][vi];
      *(float4*)(feT + (size_t)nn * PITCH2 + m0 + mhalf * 32 + mi * 16 + g * 4) =
          make_float4(A[0] + bb, A[1] + bb, A[2] + bb, A[3] + bb);
    }
  }
}

// ---------------- x2 per (cb, m') ----------------
__global__ void k_x2(const float* __restrict__ feT, float* __restrict__ x2) {
  int m = blockIdx.x * 256 + threadIdx.x;
  int cb = blockIdx.y;
  if (m >= PITCH2) return;
  const float* p = feT + (size_t)(cb * 128) * PITCH2 + m;
  float s = 0.f;
#pragma unroll 4
  for (int r = 0; r < 128; ++r) {
    float a = p[(size_t)r * PITCH2];
    s = fmaf(a, a, s);
  }
  x2[(size_t)cb * PITCH2 + m] = s;
}

// ---------------- VQ via split-bf16 MFMA: dbuf B + reg prefetch, XCD-swizzled ----
#define VQ_ISSUE_B(qq) do {                                                 \
    const u16* gh_ = cbH + (size_t)(cb * 1024 + (qq) * 64) * 128;           \
    const u16* gl_ = cbL + (size_t)(cb * 1024 + (qq) * 64) * 128;           \
    _Pragma("unroll") for (int h_ = 0; h_ < 4; ++h_) {                      \
      int id_ = tid + h_ * 256;                                             \
      int go_ = (id_ >> 4) * 128 + (id_ & 15) * 8;                          \
      rBh[h_] = *(const uint4*)&gh_[go_];                                   \
      rBl[h_] = *(const uint4*)&gl_[go_];                                   \
    }                                                                       \
  } while (0)

#define VQ_COMMIT_B(buf) do {                                               \
    _Pragma("unroll") for (int h_ = 0; h_ < 4; ++h_) {                      \
      int id_ = tid + h_ * 256;                                             \
      int row_ = id_ >> 4, c16_ = id_ & 15;                                 \
      int so_ = row_ * 128 + ((c16_ * 8) ^ ((row_ & 7) << 3));              \
      *(uint4*)&bHs[buf][so_] = rBh[h_];                                    \
      *(uint4*)&bLs[buf][so_] = rBl[h_];                                    \
    }                                                                       \
  } while (0)

__global__ __launch_bounds__(256) void k_vqmfma(
    const float* __restrict__ feT,
    const u16* __restrict__ cbH, const u16* __restrict__ cbL,
    const float* __restrict__ c2, float4* __restrict__ pb) {
  __shared__ __align__(16) u16 bHs[2][64 * 128];
  __shared__ __align__(16) u16 bLs[2][64 * 128];
  __shared__ float trip[64][2][4];

  const int j = jobmap(blockIdx.x, 190);  // 1520 jobs: mt = j>>3, r=(j&7): cb=r>>1, vh=r&1
  const int mt = j >> 3;
  const int cb = (j & 7) >> 1;
  const int vh = j & 1;
  const int tid = threadIdx.x;
  const int w = tid >> 6, l = tid & 63;
  const int mhalf = w & 1, vhalf = w >> 1;
  const int m0 = mt * 64;
  const int q0 = vh * 8, q1 = q0 + 8;

  UA aH[2][4], aL[2][4];
  {
    const int g = l >> 4;
    const float* fb = feT + (size_t)(cb * 128 + (g << 3)) * PITCH2
                      + m0 + mhalf * 32 + (l & 15);
#pragma unroll
    for (int mi = 0; mi < 2; ++mi) {
#pragma unroll
      for (int ks = 0; ks < 4; ++ks) {
#pragma unroll
        for (int jx = 0; jx < 8; ++jx) {
          float x = fb[(size_t)(ks * 32 + jx) * PITCH2 + mi * 16];
          u16 hh = bf16rne(x);
          aH[mi][ks].s[jx] = hh;
          aL[mi][ks].s[jx] = bf16rne(x - bf16tof(hh));
        }
      }
    }
  }

  uint4 rBh[4], rBl[4];
  VQ_ISSUE_B(q0);
  VQ_COMMIT_B(0);
  __syncthreads();

  float sb1[8], sb2[8];
  int si1[8];
#pragma unroll
  for (int st = 0; st < 8; ++st) { sb1[st] = FLT_MAX; sb2[st] = FLT_MAX; si1[st] = 0; }

  f32x4 acc[2][2];
#pragma unroll
  for (int mi = 0; mi < 2; ++mi)
#pragma unroll
    for (int vi = 0; vi < 2; ++vi) acc[mi][vi] = (f32x4){0.f, 0.f, 0.f, 0.f};

  const float* c2b = c2 + cb * 1024;

  int cur = 0;
  for (int q = q0; q < q1; ++q) {
    const bool more = (q + 1 < q1);
    if (more) VQ_ISSUE_B(q + 1);
    const u16* bH = bHs[cur];
    const u16* bL = bLs[cur];
    __builtin_amdgcn_s_setprio(1);
#pragma unroll
    for (int ks = 0; ks < 4; ++ks) {
      const int kbx = (ks * 32 + ((l >> 4) << 3)) ^ ((l & 7) << 3);
      const int rb = vhalf * 32 + (l & 15);
      UB b0h, b0l, b1h, b1l;
      b0h.u = *(const uint4*)&bH[rb * 128 + kbx];
      b0l.u = *(const uint4*)&bL[rb * 128 + kbx];
      b1h.u = *(const uint4*)&bH[(rb + 16) * 128 + kbx];
      b1l.u = *(const uint4*)&bL[(rb + 16) * 128 + kbx];
      acc[0][0] = MFMA16(aH[0][ks].v, b0h.v, acc[0][0]);
      acc[0][0] = MFMA16(aH[0][ks].v, b0l.v, acc[0][0]);
      acc[0][0] = MFMA16(aL[0][ks].v, b0h.v, acc[0][0]);
      acc[0][1] = MFMA16(aH[0][ks].v, b1h.v, acc[0][1]);
      acc[0][1] = MFMA16(aH[0][ks].v, b1l.v, acc[0][1]);
      acc[0][1] = MFMA16(aL[0][ks].v, b1h.v, acc[0][1]);
      acc[1][0] = MFMA16(aH[1][ks].v, b0h.v, acc[1][0]);
      acc[1][0] = MFMA16(aH[1][ks].v, b0l.v, acc[1][0]);
      acc[1][0] = MFMA16(aL[1][ks].v, b0h.v, acc[1][0]);
      acc[1][1] = MFMA16(aH[1][ks].v, b1h.v, acc[1][1]);
      acc[1][1] = MFMA16(aH[1][ks].v, b1l.v, acc[1][1]);
      acc[1][1] = MFMA16(aL[1][ks].v, b1h.v, acc[1][1]);
    }
    __builtin_amdgcn_s_setprio(0);

    // fold this chunk's distances into the running top-2
#pragma unroll
    for (int mi = 0; mi < 2; ++mi) {
#pragma unroll
      for (int vi = 0; vi < 2; ++vi) {
        const int vg = q * 64 + vhalf * 32 + vi * 16 + (l & 15);
        const float cv = c2b[vg];
        f32x4 A = acc[mi][vi];
#pragma unroll
        for (int jx = 0; jx < 4; ++jx) {
          const float s = fmaf(-2.f, A[jx], cv);
          const int st = mi * 4 + jx;
          if (s < sb1[st]) { sb2[st] = sb1[st]; sb1[st] = s; si1[st] = vg; }
          else { sb2[st] = fminf(sb2[st], s); }
        }
        acc[mi][vi] = (f32x4){0.f, 0.f, 0.f, 0.f};
      }
    }

    if (more) {
      VQ_COMMIT_B(cur ^ 1);
      __syncthreads();
      cur ^= 1;
    }
  }

#pragma unroll
  for (int st = 0; st < 8; ++st) {
    float B1 = sb1[st], B2 = sb2[st];
    int I1 = si1[st];
#pragma unroll
    for (int off = 1; off < 16; off <<= 1) {
      float oB1 = __shfl_xor(B1, off, 64);
      int oI1 = __shfl_xor(I1, off, 64);
      float oB2 = __shfl_xor(B2, off, 64);
      bool take = (oB1 < B1) || (oB1 == B1 && oI1 < I1);
      float lose = take ? B1 : oB1;
      B2 = fminf(fminf(B2, oB2), lose);
      if (take) { B1 = oB1; I1 = oI1; }
    }
    if ((l & 15) == 0) {
      int row = mhalf * 32 + (st >> 2) * 16 + (l >> 4) * 4 + (st & 3);
      trip[row][vhalf][0] = B1;
      trip[row][vhalf][1] = __int_as_float(I1);
      trip[row][vhalf][2] = B2;
    }
  }
  __syncthreads();
  if (tid < 64) {
    float B1 = trip[tid][0][0], B2 = trip[tid][0][2];
    int I1 = __float_as_int(trip[tid][0][1]);
    float oB1 = trip[tid][1][0], oB2 = trip[tid][1][2];
    int oI1 = __float_as_int(trip[tid][1][1]);
    bool take = (oB1 < B1) || (oB1 == B1 && oI1 < I1);
    float lose = take ? B1 : oB1;
    B2 = fminf(fminf(B2, oB2), lose);
    if (take) { B1 = oB1; I1 = oI1; }
    pb[(size_t)(cb * 2 + vh) * PITCH2 + m0 + tid] =
        make_float4(B1, __int_as_float(I1), B2, 0.f);
  }
}

// ---------------- select: merge 2 vhalves, eps-guard, flag near-ties -------------
#define LISTCAP 48064u
__global__ void k_vqsel(const float4* __restrict__ pb, const float* __restrict__ x2,
                        const float* __restrict__ c2mx, unsigned* __restrict__ cnt,
                        unsigned* __restrict__ list, int* __restrict__ out) {
  int ml = blockIdx.x * 256 + threadIdx.x;
  int cb = blockIdx.y;
  if (ml >= MROWS) return;
  int b = ml / TFR, t = ml - b * TFR;
  int mp = b * TFRP + 1 + t;

  float B1 = FLT_MAX, B2 = FLT_MAX;
  int I1 = 0;
#pragma unroll
  for (int vh = 0; vh < 2; ++vh) {
    float4 e = pb[(size_t)(cb * 2 + vh) * PITCH2 + mp];
    float a1 = e.x, a2 = e.z;
    int ai = __float_as_int(e.y);
    if (a1 < B1 || (a1 == B1 && ai < I1)) {
      B2 = fminf(B1, a2);
      B1 = a1;
      I1 = ai;
    } else {
      B2 = fminf(B2, a1);
    }
  }

  float xx = x2[(size_t)cb * PITCH2 + mp];
  float cm = c2mx[cb];
  float eps = 1.5e-4f * sqrtf(fmaxf(xx * cm, 0.f)) + 6e-5f * (xx + cm);
  if (!(B2 - B1 > eps)) {  // flag near-ties (and NaN) for exact recompute
    unsigned k = atomicAdd(cnt, 1u);
    if (k < LISTCAP) list[k] = ((unsigned)cb << 14) | (unsigned)mp;
  }
  out[((size_t)b * 4 + cb) * TFR + t] = I1;
}

// ---------------- exact-f32 fallback: fully coalesced (wt2f / cbTf) --------------
__global__ __launch_bounds__(256) void k_vqfix(
    const unsigned* __restrict__ cnt, const unsigned* __restrict__ list,
    const float* __restrict__ hT, const float* __restrict__ wt2f,
    const float* __restrict__ b2, const float* __restrict__ cbTf,
    const float* __restrict__ c2, int* __restrict__ out) {
  __shared__ float hcol[768];      // h values in k-order (dt*256 + ii)
  __shared__ float xs[128];
  __shared__ float rd[256];
  __shared__ int ri[256];
  const int tid = threadIdx.x;
  const unsigned n = min(*cnt, LISTCAP);
  for (unsigned i = blockIdx.x; i < n; i += gridDim.x) {
    unsigned e = list[i];
    int cb = e >> 14;
    int mp = e & 0x3FFF;
    __syncthreads();
#pragma unroll
    for (int h = 0; h < 3; ++h) {
      int kk = tid + h * 256;
      int dt = kk >> 8, ii = kk & 255;
      hcol[kk] = hT[(size_t)ii * PITCH2 + (mp + dt - 1)];
    }
    __syncthreads();
    if (tid < 128) {
      int o = cb * 128 + tid;
      float dot = 0.f;
      for (int k = 0; k < 768; ++k)
        dot = fmaf(hcol[k], wt2f[(size_t)k * 512 + o], dot);
      xs[tid] = dot + b2[o];
    }
    __syncthreads();
    float xx = 0.f;
#pragma unroll 8
    for (int d = 0; d < 128; ++d) xx = fmaf(xs[d], xs[d], xx);
    float dot4[4] = {0.f, 0.f, 0.f, 0.f};
    const float* cbase = cbTf + (size_t)(cb * 128) * 1024 + tid;
    for (int d = 0; d < 128; ++d) {
      const float* cp = cbase + (size_t)d * 1024;
      float x = xs[d];
#pragma unroll
      for (int vv = 0; vv < 4; ++vv) dot4[vv] = fmaf(x, cp[vv * 256], dot4[vv]);
    }
    float bd = FLT_MAX;
    int bi = 0;
#pragma unroll
    for (int vv = 0; vv < 4; ++vv) {
      int v = vv * 256 + tid;
      float d2 = xx - 2.f * dot4[vv] + c2[cb * 1024 + v];
      if (d2 < bd) { bd = d2; bi = v; }
    }
    rd[tid] = bd;
    ri[tid] = bi;
    __syncthreads();
    for (int s = 128; s > 0; s >>= 1) {
      if (tid < s) {
        float od = rd[tid + s];
        int oi = ri[tid + s];
        if (od < rd[tid] || (od == rd[tid] && oi < ri[tid])) { rd[tid] = od; ri[tid] = oi; }
      }
      __syncthreads();
    }
    if (tid == 0) {
      int b = mp / TFRP, t = mp % TFRP - 1;
      out[((size_t)b * 4 + cb) * TFR + t] = ri[0];
    }
  }
}

// ---------------- launch ----------------
extern "C" void kernel_launch(void* const* d_in, const int* in_sizes, int n_in,
                              void* d_out, int out_size, void* d_ws, size_t ws_size,
                              hipStream_t stream) {
  if (ws_size < WS_NEEDED) return;

  const float* wav = (const float*)d_in[0];
  const float* w1 = (const float*)d_in[1];
  const float* b1 = (const float*)d_in[2];
  const float* w2 = (const float*)d_in[3];
  const float* b2 = (const float*)d_in[4];
  const float* cbs = (const float*)d_in[5];
  int* out = (int*)d_out;

  char* W = (char*)d_ws;
  float* win = (float*)(W + OFF_WIN);
  float2* tw512 = (float2*)(W + OFF_TW512);
  float2* utw = (float2*)(W + OFF_UTW);
  float* c2mx = (float*)(W + OFF_C2MX);
  unsigned* cnt = (unsigned*)(W + OFF_CNT);
  float* melw = (float*)(W + OFF_MELW);
  int2* melsl = (int2*)(W + OFF_MELSL);
  float* wb1 = (float*)(W + OFF_WB1);
  u16* wbH2 = (u16*)(W + OFF_WBH2);
  u16* wbL2 = (u16*)(W + OFF_WBL2);
  float4* pb = (float4*)(W + OFF_PB);
  unsigned* list = (unsigned*)(W + OFF_LIST);
  float* wt2f = (float*)(W + OFF_WT2F);
  float* cbTf = (float*)(W + OFF_CBTF);
  float* c2 = (float*)(W + OFF_C2);
  u16* cbH = (u16*)(W + OFF_CBH);
  u16* cbL = (u16*)(W + OFF_CBL);
  float* x2 = (float*)(W + OFF_X2);
  float* hT = (float*)(W + OFF_HT);
  float* feT = (float*)(W + OFF_FET);
  float* lmT = (float*)(W + OFF_LMT);

  k_setup_tab<<<1, 1024, 0, stream>>>(win, tw512, utw);
  k_melw<<<1, 128, 0, stream>>>(melw, melsl);
  k_wt<<<(256 * 128 * 3 + 255) / 256, 256, 0, stream>>>(w1, wb1, 256, 128);
  k_wt2conv<<<1536, 256, 0, stream>>>(w2, wbH2, wbL2);
  k_c2<<<16, 256, 0, stream>>>(cbs, c2);
  k_c2mx<<<4, 256, 0, stream>>>(c2, c2mx, cnt);
  k_cbconv<<<512, 256, 0, stream>>>(cbs, cbH, cbL);

  k_logmel3<<<16 * 188, 256, 0, stream>>>(wav, win, tw512, utw, melw, melsl, lmT);
  k_zerocols<<<(128 * 32 + 255) / 256, 256, 0, stream>>>(lmT, 128);
  k_conv64<128, 256, 64, true><<<760, 256, 0, stream>>>(lmT, wb1, b1, hT);
  k_zerocols<<<(256 * 32 + 255) / 256, 256, 0, stream>>>(hT, 256);
  k_conv2m<<<760, 256, 0, stream>>>(hT, wbH2, wbL2, b2, feT);

  k_x2<<<dim3((PITCH2 + 255) / 256, 4), 256, 0, stream>>>(feT, x2);
  k_vqmfma<<<1520, 256, 0, stream>>>(feT, cbH, cbL, c2, pb);
  // feT dead now: build coalesced f32 tables in its region, then select + fix
  k_wt2f<<<1536, 256, 0, stream>>>(w2, wt2f);
  k_cbtf<<<2048, 256, 0, stream>>>(cbs, cbTf);
  k_vqsel<<<dim3((MROWS + 255) / 256, 4), 256, 0, stream>>>(pb, x2, c2mx, cnt, list, out);
  k_vqfix<<<2048, 256, 0, stream>>>(cnt, list, hT, wt2f, b2, cbTf, c2, out);
}

// Round 17
// 267.055 us; speedup vs baseline: 1.2296x; 1.2296x over previous
//
#include <hip/hip_runtime.h>
#include <hip/hip_bf16.h>
#include <float.h>

#define PI_D 3.14159265358979323846

// ---------------- problem constants ----------------
#define LWAV 240000
#define TFR  751             // frames per batch
#define BATCH 16
#define MROWS (BATCH * TFR)  // 12016
#define NMEL 128
#define TFRP 753             // frames + 2 halo cols per batch
#define PITCH2 12160         // 95*128 padded m' width
#define MTILES 95
#define MAXW 40

// B-tile LDS column swizzle (f32 conv1)
#define BSWZ(c) ((c) ^ ((((c) >> 5) & 3) << 2))

// ---------------- workspace layout (bytes) ----------------
#define OFF_WIN    0u
#define OFF_TW512  4096u
#define OFF_UTW    8192u
#define OFF_C2MX   12304u        // 4 f32
#define OFF_CNT    12352u        // 1 u32
#define OFF_MELW   16384u        // 128*40*4
#define OFF_MELSL  36864u
#define OFF_WB1    40960u        // 384*256*4 = 393216 -> ends 434176
#define OFF_WBH2   434176u       // 512*768*2 = 786432 (bf16-hi of w2, [n][k])
#define OFF_WBL2   1220608u      // 786432 -> ends 2007040
#define OFF_PB     434176u       //   overlay after conv2m: 8*12160*16 = 1556480 (ends 1990656)
#define OFF_C2     2007040u      // 4*1024*4
#define OFF_CBH    2023424u      // 4096*128*2 = 1048576
#define OFF_CBL    3072000u      // -> ends 4120576
#define OFF_X2     4120576u      // 4*12160*4 -> ends 4315136
#define OFF_HT     4317184u      // 256*12160*4 = 12451840 (ALIVE through vqfix)
#define OFF_FET    16777216u     // 512*12160*4 = 24903680 -> ends 41680896
#define OFF_LMT    OFF_FET       //   overlay (lmT dead before conv2m writes feT)
// post-vqmfma overlays inside the dead feT region:
#define OFF_LIST   OFF_FET                  // 48064*4 = 192256
#define OFF_WT2F   (OFF_FET + 262144u)      // 768*512*4 = 1572864 -> ends 18612224
#define OFF_CBTF   18612224u                // 4*128*1024*4 = 2097152 -> ends 20709376
#define WS_NEEDED  41685000u

typedef unsigned short u16;
typedef __attribute__((ext_vector_type(8))) __bf16 bf16x8;
typedef __attribute__((ext_vector_type(4))) float f32x4;
union UB { uint4 u; bf16x8 v; };
union UA { u16 s[8]; bf16x8 v; };

__device__ __forceinline__ u16 bf16rne(float x) {
  unsigned u = __float_as_uint(x);
  return (u16)((u + 0x7FFFu + ((u >> 16) & 1u)) >> 16);
}
__device__ __forceinline__ float bf16tof(u16 h) {
  return __uint_as_float(((unsigned)h) << 16);
}

// XCD-aware job remap: grid is 1-D with G = 8*GP blocks. Jobs that share an
// A-tile are CONSECUTIVE job ids; this mapping gives each XCD (bid%8) a
// contiguous job chunk -> sharers land on one XCD's L2.
__device__ __forceinline__ int jobmap(int bid, int GP) {
  return (bid & 7) * GP + (bid >> 3);
}

// ---------------- setup kernels ----------------
__global__ void k_setup_tab(float* __restrict__ win, float2* __restrict__ tw512,
                            float2* __restrict__ utw) {
  int t = threadIdx.x;
  if (t < 1024) {
    double v = 0.5 * (1.0 - cos(2.0 * PI_D * (double)t / 1024.0));
    win[t] = (float)v;
  }
  if (t < 512) {
    double a = -2.0 * PI_D * (double)t / 512.0;
    tw512[t] = make_float2((float)cos(a), (float)sin(a));
  }
  if (t < 513) {
    double a = -2.0 * PI_D * (double)t / 1024.0;
    utw[t] = make_float2((float)cos(a), (float)sin(a));
  }
}

__device__ __forceinline__ double fpt_d(int j) {
  double melmax = 2595.0 * log10(1.0 + 12000.0 / 700.0);
  double mp = melmax * (double)j / 129.0;
  return 700.0 * (pow(10.0, mp / 2595.0) - 1.0);
}

__global__ void k_melw(float* __restrict__ melw, int2* __restrict__ melsl) {
  int m = threadIdx.x;
  double f0 = fpt_d(m), f1 = fpt_d(m + 1), f2 = fpt_d(m + 2);
  const double binw = 12000.0 / 512.0;
  int s = (int)floor(f0 / binw) + 1;
  if (s < 0) s = 0;
  int e = (int)ceil(f2 / binw) - 1;
  if (e > 512) e = 512;
  int len = e - s + 1;
  if (len < 0) len = 0;
  if (len > MAXW) len = MAXW;
  melsl[m] = make_int2(s, len);
  for (int j = 0; j < MAXW; ++j) {
    double freq = binw * (double)(s + j);
    double down = (freq - f0) / (f1 - f0);
    double up = (f2 - freq) / (f2 - f1);
    double v = fmin(down, up);
    v = fmax(0.0, v);
    melw[m * MAXW + j] = (j < len) ? (float)v : 0.f;
  }
}

// conv1 weights (f32): wt[(dt*C+i)*O + o] = w[(o*C+i)*3 + dt]
__global__ void k_wt(const float* __restrict__ w, float* __restrict__ wt,
                     int O, int C) {
  int idx = blockIdx.x * 256 + threadIdx.x;
  int total = O * C * 3;
  if (idx >= total) return;
  int o = idx % O;
  int rest = idx / O;
  int i = rest % C;
  int dt = rest / C;
  wt[(dt * C + i) * O + o] = w[(o * C + i) * 3 + dt];
}

// conv2 weights: bf16 hi/lo split, layout [o][k] with k = dt*256 + i
__global__ void k_wt2conv(const float* __restrict__ w2, u16* __restrict__ wbH2,
                          u16* __restrict__ wbL2) {
  int idx = blockIdx.x * 256 + threadIdx.x;  // 512*768 = 393216
  if (idx >= 512 * 768) return;
  int o = idx / 768;
  int k = idx - o * 768;
  int dt = k >> 8, i = k & 255;
  float x = w2[(size_t)(o * 256 + i) * 3 + dt];
  u16 hh = bf16rne(x);
  wbH2[idx] = hh;
  wbL2[idx] = bf16rne(x - bf16tof(hh));
}

// f32 transposed conv2 weights: wt2f[k*512 + o] = w2[o][k], k = dt*256+i
__global__ void k_wt2f(const float* __restrict__ w2, float* __restrict__ wt2f) {
  int idx = blockIdx.x * 256 + threadIdx.x;  // 393216
  if (idx >= 768 * 512) return;
  int o = idx & 511, k = idx >> 9;
  int dt = k >> 8, i = k & 255;
  wt2f[idx] = w2[(size_t)(o * 256 + i) * 3 + dt];
}

// f32 transposed codebooks: cbTf[(cb*128+d)*1024 + v] = cbs[(cb*1024+v)*128 + d]
__global__ void k_cbtf(const float* __restrict__ cbs, float* __restrict__ cbTf) {
  int idx = blockIdx.x * 256 + threadIdx.x;  // 524288
  int v = idx & 1023;
  int d = (idx >> 10) & 127;
  int cb = idx >> 17;
  cbTf[idx] = cbs[(size_t)((cb << 10) + v) * 128 + d];
}

__global__ void k_c2(const float* __restrict__ cb, float* __restrict__ c2) {
  int v = blockIdx.x * 256 + threadIdx.x;
  if (v >= 4096) return;
  const float* r = cb + (size_t)v * 128;
  float s = 0.f;
#pragma unroll 8
  for (int i = 0; i < 128; ++i) s = fmaf(r[i], r[i], s);
  c2[v] = s;
}

__global__ void k_c2mx(const float* __restrict__ c2, float* __restrict__ c2mx,
                       unsigned* __restrict__ cnt) {
  __shared__ float red[256];
  int cb = blockIdx.x, tid = threadIdx.x;
  float m = 0.f;
  for (int v = tid; v < 1024; v += 256) m = fmaxf(m, c2[cb * 1024 + v]);
  red[tid] = m;
  __syncthreads();
  for (int s = 128; s > 0; s >>= 1) {
    if (tid < s) red[tid] = fmaxf(red[tid], red[tid + s]);
    __syncthreads();
  }
  if (tid == 0) {
    c2mx[cb] = red[0];
    if (cb == 0) *cnt = 0u;
  }
}

__global__ void k_cbconv(const float* __restrict__ cbs, u16* __restrict__ cbH,
                         u16* __restrict__ cbL) {
  int id = blockIdx.x * 256 + threadIdx.x;  // 131072
  int v = id >> 5, d4 = (id & 31) * 4;
  float4 x = *(const float4*)(cbs + (size_t)v * 128 + d4);
  const float xs[4] = {x.x, x.y, x.z, x.w};
  unsigned wh[2], wl[2];
#pragma unroll
  for (int p = 0; p < 2; ++p) {
    u16 h0 = bf16rne(xs[2 * p]);
    u16 h1 = bf16rne(xs[2 * p + 1]);
    u16 l0 = bf16rne(xs[2 * p] - bf16tof(h0));
    u16 l1 = bf16rne(xs[2 * p + 1] - bf16tof(h1));
    wh[p] = (unsigned)h0 | ((unsigned)h1 << 16);
    wl[p] = (unsigned)l0 | ((unsigned)l1 << 16);
  }
  *(uint2*)(cbH + (size_t)v * 128 + d4) = make_uint2(wh[0], wh[1]);
  *(uint2*)(cbL + (size_t)v * 128 + d4) = make_uint2(wl[0], wl[1]);
}

__global__ void k_zerocols(float* __restrict__ a, int rows) {
  int tid = blockIdx.x * 256 + threadIdx.x;
  int col_id = tid & 31;
  int r = tid >> 5;
  if (r >= rows) return;
  int bq = col_id >> 1;
  int c = bq * TFRP + ((col_id & 1) ? 752 : 0);
  a[(size_t)r * PITCH2 + c] = 0.f;
}

// ---------------- complex helpers / radix-8 DFT ----------------
__device__ __forceinline__ float2 cadd(float2 a, float2 b) { return make_float2(a.x + b.x, a.y + b.y); }
__device__ __forceinline__ float2 csub(float2 a, float2 b) { return make_float2(a.x - b.x, a.y - b.y); }
__device__ __forceinline__ float2 cmul(float2 a, float2 b) {
  return make_float2(a.x * b.x - a.y * b.y, a.x * b.y + a.y * b.x);
}
__device__ __forceinline__ float2 mulnegi(float2 a) { return make_float2(a.y, -a.x); }

__device__ __forceinline__ void dft8(const float2* d, float2* o) {
  const float S = 0.70710678118654752440f;
  float2 f0 = cadd(d[0], d[4]), f1 = csub(d[0], d[4]);
  float2 f2 = cadd(d[2], d[6]), f3 = csub(d[2], d[6]);
  float2 h0 = cadd(d[1], d[5]), h1 = csub(d[1], d[5]);
  float2 h2 = cadd(d[3], d[7]), h3 = csub(d[3], d[7]);
  float2 E0 = cadd(f0, f2), E2 = csub(f0, f2);
  float2 nif3 = mulnegi(f3);
  float2 E1 = cadd(f1, nif3), E3 = csub(f1, nif3);
  float2 O0 = cadd(h0, h2), O2 = csub(h0, h2);
  float2 nih3 = mulnegi(h3);
  float2 O1 = cadd(h1, nih3), O3 = csub(h1, nih3);
  float2 w1o = make_float2(S * (O1.x + O1.y), S * (O1.y - O1.x));
  float2 w2o = mulnegi(O2);
  float2 w3o = make_float2(S * (O3.y - O3.x), -S * (O3.x + O3.y));
  o[0] = cadd(E0, O0);  o[4] = csub(E0, O0);
  o[1] = cadd(E1, w1o); o[5] = csub(E1, w1o);
  o[2] = cadd(E2, w2o); o[6] = csub(E2, w2o);
  o[3] = cadd(E3, w3o); o[7] = csub(E3, w3o);
}

__device__ __forceinline__ float powspec(const float2* Z, const float2* __restrict__ utw,
                                         int k) {
  float2 Zk = Z[k & 511];
  float2 Zm = Z[(512 - k) & 511];
  float2 ut = utw[k];
  float fer = 0.5f * (Zk.x + Zm.x);
  float fei = 0.5f * (Zk.y - Zm.y);
  float fo_r = 0.5f * (Zk.y + Zm.y);
  float fo_i = -0.5f * (Zk.x - Zm.x);
  float xr = fer + ut.x * fo_r - ut.y * fo_i;
  float xi = fei + ut.x * fo_i + ut.y * fo_r;
  return xr * xr + xi * xi;
}

// ---------------- log-mel ----------------
__global__ __launch_bounds__(256) void k_logmel3(
    const float* __restrict__ wav, const float* __restrict__ win,
    const float2* __restrict__ tw512, const float2* __restrict__ utw,
    const float* __restrict__ melw, const int2* __restrict__ melsl,
    float* __restrict__ lmT) {
  __shared__ float2 zbuf[4][512];
  __shared__ float pbuf[4][516];
  __shared__ float mex[128][5];

  const int w = threadIdx.x >> 6;
  const int t = threadIdx.x & 63;
  const int bq = blockIdx.x / 188;
  const int t0 = (blockIdx.x % 188) * 4;
  const int tt = min(t0 + w, TFR - 1);
  const float* wv = wav + (size_t)bq * LWAV;
  float2* Z = zbuf[w];
  float* p = pbuf[w];

  const int base = tt * 320 - 512;

  float2 c[8];
  if (base >= 0 && base + 1024 <= LWAV) {
    const float2* wv2 = (const float2*)(wv + base);
    const float2* wn2 = (const float2*)win;
#pragma unroll
    for (int j = 0; j < 8; ++j) {
      int mm = t + 64 * j;
      float2 xv = wv2[mm];
      float2 wn = wn2[mm];
      c[j] = make_float2(xv.x * wn.x, xv.y * wn.y);
    }
  } else {
#pragma unroll
    for (int j = 0; j < 8; ++j) {
      int mm = t + 64 * j;
      int n0 = base + 2 * mm, n1 = n0 + 1;
      int j0 = n0 < 0 ? -n0 : (n0 >= LWAV ? 2 * LWAV - 2 - n0 : n0);
      int j1 = n1 < 0 ? -n1 : (n1 >= LWAV ? 2 * LWAV - 2 - n1 : n1);
      c[j] = make_float2(wv[j0] * win[2 * mm], wv[j1] * win[2 * mm + 1]);
    }
  }

  float2 e[8];
  dft8(c, e);
#pragma unroll
  for (int pp = 1; pp < 8; ++pp) e[pp] = cmul(e[pp], tw512[(t * pp) & 511]);
#pragma unroll
  for (int pp = 0; pp < 8; ++pp) Z[pp * 64 + (t ^ (pp << 3))] = e[pp];
  asm volatile("s_waitcnt lgkmcnt(0)" ::: "memory");

  const int P = t >> 3, M = t & 7;
  float2 g[8];
#pragma unroll
  for (int v = 0; v < 8; ++v) g[v] = Z[P * 64 + ((M + 8 * v) ^ (P << 3))];
  asm volatile("s_waitcnt lgkmcnt(0)" ::: "memory");

  float2 y[8];
  dft8(g, y);
#pragma unroll
  for (int aa = 1; aa < 8; ++aa) y[aa] = cmul(y[aa], tw512[(8 * M * aa) & 511]);
#pragma unroll
  for (int aa = 0; aa < 8; ++aa) Z[aa * 64 + (((M << 3) + P) ^ (aa << 3))] = y[aa];
  asm volatile("s_waitcnt lgkmcnt(0)" ::: "memory");

  float2 yv[8];
#pragma unroll
  for (int u = 0; u < 8; ++u) yv[u] = Z[P * 64 + (((u << 3) + M) ^ (P << 3))];
  asm volatile("s_waitcnt lgkmcnt(0)" ::: "memory");

  float2 X[8];
  dft8(yv, X);
#pragma unroll
  for (int bb = 0; bb < 8; ++bb) Z[bb * 64 + t] = X[bb];
  asm volatile("s_waitcnt lgkmcnt(0)" ::: "memory");

#pragma unroll
  for (int j = 0; j < 8; ++j) {
    int k = t + 64 * j;
    p[k] = powspec(Z, utw, k);
  }
  if (t == 0) p[512] = powspec(Z, utw, 512);
  asm volatile("s_waitcnt lgkmcnt(0)" ::: "memory");

#pragma unroll
  for (int h = 0; h < 2; ++h) {
    int m = 2 * t + h;
    int2 sl = melsl[m];
    float acc = 0.f;
    const float* wrow = melw + m * MAXW;
    for (int j = 0; j < sl.y; ++j) acc = fmaf(p[sl.x + j], wrow[j], acc);
    mex[m][w] = logf(fmaxf(acc, 1e-5f));
  }
  __syncthreads();
  if (threadIdx.x < 128) {
    int cc = threadIdx.x;
    float* op = lmT + (size_t)cc * PITCH2 + (size_t)bq * TFRP + 1 + t0;
    op[0] = mex[cc][0];
    op[1] = mex[cc][1];
    op[2] = mex[cc][2];
    op[3] = mex[cc][3];
  }
}

// ---------------- conv1: f32 64m x 64n GEMM, XCD-swizzled 1-D grid (760) ---------
template <int C, int N, int BN, bool GELU>
__global__ __launch_bounds__(256) void k_conv64(const float* __restrict__ in,
                                                const float* __restrict__ wt,
                                                const float* __restrict__ bias,
                                                float* __restrict__ out) {
  constexpr int K = 3 * C;
  constexpr int NC = BN / 16;
  __shared__ float At[32 * 64];
  __shared__ float Bt[32 * BN];
  const int j = jobmap(blockIdx.x, 95);   // 760 jobs: mt = j>>2, nb = j&3
  const int m0 = (j >> 2) * 64;
  const int n0 = (j & 3) * BN;
  const int tid = threadIdx.x;
  const int tm = tid >> 4, tn = tid & 15;

  int bco[NC / 4];
#pragma unroll
  for (int i = 0; i < NC / 4; ++i) bco[i] = BSWZ(tn * NC + i * 4);

  float acc[4][NC] = {};

  for (int k0 = 0; k0 < K; k0 += 32) {
    const int dt = k0 / C;
    const int i0 = k0 - dt * C;
    const float* asrc = in + (size_t)i0 * PITCH2 + (m0 + dt - 1);
    const float* bsrc = wt + (size_t)k0 * N + n0;
#pragma unroll
    for (int h = 0; h < 2; ++h) {
      const int id = tid + h * 256;
      const int r = id >> 4, cf = (id & 15) * 4;
      const float* ap = asrc + (size_t)r * PITCH2 + cf;
      *(float4*)&At[r * 64 + cf] = make_float4(ap[0], ap[1], ap[2], ap[3]);
    }
#pragma unroll
    for (int h = 0; h < BN / 32; ++h) {
      const int id = tid + h * 256;
      const int r = id / (BN / 4), cf = (id % (BN / 4)) * 4;
      *(float4*)&Bt[r * BN + BSWZ(cf)] = *(const float4*)(bsrc + (size_t)r * N + cf);
    }
    __syncthreads();
#pragma unroll
    for (int kc = 0; kc < 32; ++kc) {
      float4 a = *(const float4*)&At[kc * 64 + tm * 4];
      float av[4] = {a.x, a.y, a.z, a.w};
      float bv[NC];
#pragma unroll
      for (int i = 0; i < NC / 4; ++i) {
        float4 b = *(const float4*)&Bt[kc * BN + bco[i]];
        bv[i * 4] = b.x; bv[i * 4 + 1] = b.y; bv[i * 4 + 2] = b.z; bv[i * 4 + 3] = b.w;
      }
#pragma unroll
      for (int r = 0; r < 4; ++r)
#pragma unroll
        for (int cq = 0; cq < NC; ++cq) acc[r][cq] = fmaf(av[r], bv[cq], acc[r][cq]);
    }
    __syncthreads();
  }

#pragma unroll
  for (int cq = 0; cq < NC; ++cq) {
    const int n = n0 + tn * NC + cq;
    const float bb = bias[n];
    float vv[4];
#pragma unroll
    for (int r = 0; r < 4; ++r) {
      float v = acc[r][cq] + bb;
      if (GELU) v = 0.5f * v * (1.0f + erff(v * 0.7071067811865476f));
      vv[r] = v;
    }
    *(float4*)(out + (size_t)n * PITCH2 + m0 + tm * 4) =
        make_float4(vv[0], vv[1], vv[2], vv[3]);
  }
}

// ---------------- conv2 via split-bf16 MFMA, dbuf+prefetch, XCD-swizzled ---------
#define MFMA16(a, b, c) __builtin_amdgcn_mfma_f32_16x16x32_bf16((a), (b), (c), 0, 0, 0)

#define C2M_ISSUE_A(dst, cc) do {                                           \
    const int kc0_ = (cc) * 32;                                             \
    const int dt_ = kc0_ >> 8, i0_ = kc0_ & 255;                            \
    const float* hb_ = hT + (size_t)(i0_ + g * 8) * PITCH2                  \
                       + m0 + mhalf * 32 + ln + dt_ - 1;                    \
    _Pragma("unroll") for (int mi_ = 0; mi_ < 2; ++mi_)                     \
      _Pragma("unroll") for (int j_ = 0; j_ < 8; ++j_)                      \
        dst[mi_][j_] = hb_[(size_t)j_ * PITCH2 + mi_ * 16];                 \
  } while (0)

#define C2M_ISSUE_B(cc) do {                                                \
    const int kc0_ = (cc) * 32;                                             \
    _Pragma("unroll") for (int h2_ = 0; h2_ < 2; ++h2_) {                   \
      const int id_ = tid + h2_ * 256;                                      \
      const int nn_ = id_ >> 2, part_ = id_ & 3;                            \
      const size_t src_ = (size_t)(n0 + nn_) * 768 + kc0_ + part_ * 8;      \
      rBh[h2_] = *(const uint4*)(wbH2 + src_);                              \
      rBl[h2_] = *(const uint4*)(wbL2 + src_);                              \
    }                                                                       \
  } while (0)

#define C2M_COMMIT_B(buf) do {                                              \
    _Pragma("unroll") for (int h2_ = 0; h2_ < 2; ++h2_) {                   \
      const int id_ = tid + h2_ * 256;                                      \
      const int nn_ = id_ >> 2, part_ = id_ & 3;                            \
      *(uint4*)&bHs[buf][nn_ * 40 + part_ * 8] = rBh[h2_];                  \
      *(uint4*)&bLs[buf][nn_ * 40 + part_ * 8] = rBl[h2_];                  \
    }                                                                       \
  } while (0)

__global__ __launch_bounds__(256) void k_conv2m(
    const float* __restrict__ hT,
    const u16* __restrict__ wbH2, const u16* __restrict__ wbL2,
    const float* __restrict__ b2, float* __restrict__ feT) {
  __shared__ __align__(16) u16 bHs[2][128 * 40];  // [buf][n][32k + 8 pad]
  __shared__ __align__(16) u16 bLs[2][128 * 40];
  const int j = jobmap(blockIdx.x, 95);   // 760 jobs: mt = j>>2, nq = j&3
  const int mt = j >> 2;
  const int nq = j & 3;
  const int tid = threadIdx.x;
  const int w = tid >> 6, l = tid & 63;
  const int mhalf = w & 1, nhalf = w >> 1;
  const int g = l >> 4, ln = l & 15;
  const int m0 = mt * 64;
  const int n0 = nq * 128;

  f32x4 acc[2][4];
#pragma unroll
  for (int mi = 0; mi < 2; ++mi)
#pragma unroll
    for (int vi = 0; vi < 4; ++vi) acc[mi][vi] = (f32x4){0.f, 0.f, 0.f, 0.f};

  float rA[2][8], rA2[2][8];
  uint4 rBh[2], rBl[2];

  C2M_ISSUE_A(rA, 0);
  C2M_ISSUE_B(0);
  C2M_COMMIT_B(0);
  __syncthreads();

  int cur = 0;
  for (int cc = 0; cc < 24; ++cc) {
    const bool more = (cc + 1 < 24);
    if (more) { C2M_ISSUE_B(cc + 1); C2M_ISSUE_A(rA2, cc + 1); }
    UA aH[2], aL[2];
#pragma unroll
    for (int mi = 0; mi < 2; ++mi)
#pragma unroll
      for (int jx = 0; jx < 8; ++jx) {
        u16 hh = bf16rne(rA[mi][jx]);
        aH[mi].s[jx] = hh;
        aL[mi].s[jx] = bf16rne(rA[mi][jx] - bf16tof(hh));
      }
    const u16* bH = bHs[cur];
    const u16* bL = bLs[cur];
    __builtin_amdgcn_s_setprio(1);
#pragma unroll
    for (int vi = 0; vi < 4; ++vi) {
      const int nn = nhalf * 64 + vi * 16 + ln;
      UB bh, bl;
      bh.u = *(const uint4*)&bH[nn * 40 + g * 8];
      bl.u = *(const uint4*)&bL[nn * 40 + g * 8];
#pragma unroll
      for (int mi = 0; mi < 2; ++mi) {
        acc[mi][vi] = MFMA16(aH[mi].v, bh.v, acc[mi][vi]);
        acc[mi][vi] = MFMA16(aH[mi].v, bl.v, acc[mi][vi]);
        acc[mi][vi] = MFMA16(aL[mi].v, bh.v, acc[mi][vi]);
      }
    }
    __builtin_amdgcn_s_setprio(0);
    if (more) {
      C2M_COMMIT_B(cur ^ 1);
      __syncthreads();
      cur ^= 1;
#pragma unroll
      for (int mi = 0; mi < 2; ++mi)
#pragma unroll
        for (int jx = 0; jx < 8; ++jx) rA[mi][jx] = rA2[mi][jx];
    }
  }

#pragma unroll
  for (int vi = 0; vi < 4; ++vi) {
    const int nn = n0 + nhalf * 64 + vi * 16 + ln;
    const float bb = b2[nn];
#pragma unroll
    for (int mi = 0; mi < 2; ++mi) {
      f32x4 A = acc[mi][vi];
      *(float4*)(feT + (size_t)nn * PITCH2 + m0 + mhalf * 32 + mi * 16 + g * 4) =
          make_float4(A[0] + bb, A[1] + bb, A[2] + bb, A[3] + bb);
    }
  }
}

// ---------------- x2 per (cb, m') ----------------
__global__ void k_x2(const float* __restrict__ feT, float* __restrict__ x2) {
  int m = blockIdx.x * 256 + threadIdx.x;
  int cb = blockIdx.y;
  if (m >= PITCH2) return;
  const float* p = feT + (size_t)(cb * 128) * PITCH2 + m;
  float s = 0.f;
#pragma unroll 4
  for (int r = 0; r < 128; ++r) {
    float a = p[(size_t)r * PITCH2];
    s = fmaf(a, a, s);
  }
  x2[(size_t)cb * PITCH2 + m] = s;
}

// ---------------- VQ via split-bf16 MFMA: round-15 form (single buffer) ----------
__global__ __launch_bounds__(256) void k_vqmfma(
    const float* __restrict__ feT,
    const u16* __restrict__ cbH, const u16* __restrict__ cbL,
    const float* __restrict__ c2, float4* __restrict__ pb) {
  __shared__ __align__(16) u16 bHs[64 * 128];
  __shared__ __align__(16) u16 bLs[64 * 128];
  __shared__ float trip[64][2][4];

  const int j = jobmap(blockIdx.x, 190);  // 1520 jobs: mt = j>>3, r=(j&7): cb=r>>1, vh=r&1
  const int mt = j >> 3;
  const int cb = (j & 7) >> 1;
  const int vh = j & 1;
  const int tid = threadIdx.x;
  const int w = tid >> 6, l = tid & 63;
  const int mhalf = w & 1, vhalf = w >> 1;
  const int m0 = mt * 64;
  const int q0 = vh * 8, q1 = q0 + 8;

  UA aH[2][4], aL[2][4];
  {
    const int g = l >> 4;
    const float* fb = feT + (size_t)(cb * 128 + (g << 3)) * PITCH2
                      + m0 + mhalf * 32 + (l & 15);
#pragma unroll
    for (int mi = 0; mi < 2; ++mi) {
#pragma unroll
      for (int ks = 0; ks < 4; ++ks) {
#pragma unroll
        for (int jx = 0; jx < 8; ++jx) {
          float x = fb[(size_t)(ks * 32 + jx) * PITCH2 + mi * 16];
          u16 hh = bf16rne(x);
          aH[mi][ks].s[jx] = hh;
          aL[mi][ks].s[jx] = bf16rne(x - bf16tof(hh));
        }
      }
    }
  }

  {
    const u16* gh = cbH + (size_t)(cb * 1024 + q0 * 64) * 128;
    const u16* gl = cbL + (size_t)(cb * 1024 + q0 * 64) * 128;
#pragma unroll
    for (int h = 0; h < 4; ++h) {
      int id = tid + h * 256;
      int row = id >> 4, c16 = id & 15;
      int go = row * 128 + c16 * 8;
      int so = row * 128 + ((c16 * 8) ^ ((row & 7) << 3));
      *(uint4*)&bHs[so] = *(const uint4*)&gh[go];
      *(uint4*)&bLs[so] = *(const uint4*)&gl[go];
    }
  }
  __syncthreads();

  float sb1[8], sb2[8];
  int si1[8];
#pragma unroll
  for (int st = 0; st < 8; ++st) { sb1[st] = FLT_MAX; sb2[st] = FLT_MAX; si1[st] = 0; }

  f32x4 acc[2][2];
#pragma unroll
  for (int mi = 0; mi < 2; ++mi)
#pragma unroll
    for (int vi = 0; vi < 2; ++vi) acc[mi][vi] = (f32x4){0.f, 0.f, 0.f, 0.f};

  const float* c2b = c2 + cb * 1024;

  for (int q = q0; q < q1; ++q) {
#pragma unroll
    for (int ks = 0; ks < 4; ++ks) {
      const int kbx = (ks * 32 + ((l >> 4) << 3)) ^ ((l & 7) << 3);
      const int rb = vhalf * 32 + (l & 15);
      UB b0h, b0l, b1h, b1l;
      b0h.u = *(const uint4*)&bHs[rb * 128 + kbx];
      b0l.u = *(const uint4*)&bLs[rb * 128 + kbx];
      b1h.u = *(const uint4*)&bHs[(rb + 16) * 128 + kbx];
      b1l.u = *(const uint4*)&bLs[(rb + 16) * 128 + kbx];
      acc[0][0] = MFMA16(aH[0][ks].v, b0h.v, acc[0][0]);
      acc[0][0] = MFMA16(aH[0][ks].v, b0l.v, acc[0][0]);
      acc[0][0] = MFMA16(aL[0][ks].v, b0h.v, acc[0][0]);
      acc[0][1] = MFMA16(aH[0][ks].v, b1h.v, acc[0][1]);
      acc[0][1] = MFMA16(aH[0][ks].v, b1l.v, acc[0][1]);
      acc[0][1] = MFMA16(aL[0][ks].v, b1h.v, acc[0][1]);
      acc[1][0] = MFMA16(aH[1][ks].v, b0h.v, acc[1][0]);
      acc[1][0] = MFMA16(aH[1][ks].v, b0l.v, acc[1][0]);
      acc[1][0] = MFMA16(aL[1][ks].v, b0h.v, acc[1][0]);
      acc[1][1] = MFMA16(aH[1][ks].v, b1h.v, acc[1][1]);
      acc[1][1] = MFMA16(aH[1][ks].v, b1l.v, acc[1][1]);
      acc[1][1] = MFMA16(aL[1][ks].v, b1h.v, acc[1][1]);
    }

#pragma unroll
    for (int mi = 0; mi < 2; ++mi) {
#pragma unroll
      for (int vi = 0; vi < 2; ++vi) {
        const int vg = q * 64 + vhalf * 32 + vi * 16 + (l & 15);
        const float cv = c2b[vg];
        f32x4 A = acc[mi][vi];
#pragma unroll
        for (int jx = 0; jx < 4; ++jx) {
          const float s = fmaf(-2.f, A[jx], cv);
          const int st = mi * 4 + jx;
          if (s < sb1[st]) { sb2[st] = sb1[st]; sb1[st] = s; si1[st] = vg; }
          else { sb2[st] = fminf(sb2[st], s); }
        }
        acc[mi][vi] = (f32x4){0.f, 0.f, 0.f, 0.f};
      }
    }

    if (q + 1 < q1) {
      __syncthreads();
      const u16* gh = cbH + (size_t)(cb * 1024 + (q + 1) * 64) * 128;
      const u16* gl = cbL + (size_t)(cb * 1024 + (q + 1) * 64) * 128;
#pragma unroll
      for (int h = 0; h < 4; ++h) {
        int id = tid + h * 256;
        int row = id >> 4, c16 = id & 15;
        int go = row * 128 + c16 * 8;
        int so = row * 128 + ((c16 * 8) ^ ((row & 7) << 3));
        *(uint4*)&bHs[so] = *(const uint4*)&gh[go];
        *(uint4*)&bLs[so] = *(const uint4*)&gl[go];
      }
      __syncthreads();
    }
  }

#pragma unroll
  for (int st = 0; st < 8; ++st) {
    float B1 = sb1[st], B2 = sb2[st];
    int I1 = si1[st];
#pragma unroll
    for (int off = 1; off < 16; off <<= 1) {
      float oB1 = __shfl_xor(B1, off, 64);
      int oI1 = __shfl_xor(I1, off, 64);
      float oB2 = __shfl_xor(B2, off, 64);
      bool take = (oB1 < B1) || (oB1 == B1 && oI1 < I1);
      float lose = take ? B1 : oB1;
      B2 = fminf(fminf(B2, oB2), lose);
      if (take) { B1 = oB1; I1 = oI1; }
    }
    if ((l & 15) == 0) {
      int row = mhalf * 32 + (st >> 2) * 16 + (l >> 4) * 4 + (st & 3);
      trip[row][vhalf][0] = B1;
      trip[row][vhalf][1] = __int_as_float(I1);
      trip[row][vhalf][2] = B2;
    }
  }
  __syncthreads();
  if (tid < 64) {
    float B1 = trip[tid][0][0], B2 = trip[tid][0][2];
    int I1 = __float_as_int(trip[tid][0][1]);
    float oB1 = trip[tid][1][0], oB2 = trip[tid][1][2];
    int oI1 = __float_as_int(trip[tid][1][1]);
    bool take = (oB1 < B1) || (oB1 == B1 && oI1 < I1);
    float lose = take ? B1 : oB1;
    B2 = fminf(fminf(B2, oB2), lose);
    if (take) { B1 = oB1; I1 = oI1; }
    pb[(size_t)(cb * 2 + vh) * PITCH2 + m0 + tid] =
        make_float4(B1, __int_as_float(I1), B2, 0.f);
  }
}

// ---------------- select: merge 2 vhalves, eps-guard, flag near-ties -------------
#define LISTCAP 48064u
__global__ void k_vqsel(const float4* __restrict__ pb, const float* __restrict__ x2,
                        const float* __restrict__ c2mx, unsigned* __restrict__ cnt,
                        unsigned* __restrict__ list, int* __restrict__ out) {
  int ml = blockIdx.x * 256 + threadIdx.x;
  int cb = blockIdx.y;
  if (ml >= MROWS) return;
  int b = ml / TFR, t = ml - b * TFR;
  int mp = b * TFRP + 1 + t;

  float B1 = FLT_MAX, B2 = FLT_MAX;
  int I1 = 0;
#pragma unroll
  for (int vh = 0; vh < 2; ++vh) {
    float4 e = pb[(size_t)(cb * 2 + vh) * PITCH2 + mp];
    float a1 = e.x, a2 = e.z;
    int ai = __float_as_int(e.y);
    if (a1 < B1 || (a1 == B1 && ai < I1)) {
      B2 = fminf(B1, a2);
      B1 = a1;
      I1 = ai;
    } else {
      B2 = fminf(B2, a1);
    }
  }

  float xx = x2[(size_t)cb * PITCH2 + mp];
  float cm = c2mx[cb];
  float eps = 1.5e-4f * sqrtf(fmaxf(xx * cm, 0.f)) + 6e-5f * (xx + cm);
  if (!(B2 - B1 > eps)) {  // flag near-ties (and NaN) for exact recompute
    unsigned k = atomicAdd(cnt, 1u);
    if (k < LISTCAP) list[k] = ((unsigned)cb << 14) | (unsigned)mp;
  }
  out[((size_t)b * 4 + cb) * TFR + t] = I1;
}

// ---------------- exact-f32 fallback: fully coalesced (wt2f / cbTf) --------------
__global__ __launch_bounds__(256) void k_vqfix(
    const unsigned* __restrict__ cnt, const unsigned* __restrict__ list,
    const float* __restrict__ hT, const float* __restrict__ wt2f,
    const float* __restrict__ b2, const float* __restrict__ cbTf,
    const float* __restrict__ c2, int* __restrict__ out) {
  __shared__ float hcol[768];      // h values in k-order (dt*256 + ii)
  __shared__ float xs[128];
  __shared__ float rd[256];
  __shared__ int ri[256];
  const int tid = threadIdx.x;
  const unsigned n = min(*cnt, LISTCAP);
  for (unsigned i = blockIdx.x; i < n; i += gridDim.x) {
    unsigned e = list[i];
    int cb = e >> 14;
    int mp = e & 0x3FFF;
    __syncthreads();
#pragma unroll
    for (int h = 0; h < 3; ++h) {
      int kk = tid + h * 256;
      int dt = kk >> 8, ii = kk & 255;
      hcol[kk] = hT[(size_t)ii * PITCH2 + (mp + dt - 1)];
    }
    __syncthreads();
    if (tid < 128) {
      int o = cb * 128 + tid;
      float dot = 0.f;
      for (int k = 0; k < 768; ++k)
        dot = fmaf(hcol[k], wt2f[(size_t)k * 512 + o], dot);
      xs[tid] = dot + b2[o];
    }
    __syncthreads();
    float xx = 0.f;
#pragma unroll 8
    for (int d = 0; d < 128; ++d) xx = fmaf(xs[d], xs[d], xx);
    float dot4[4] = {0.f, 0.f, 0.f, 0.f};
    const float* cbase = cbTf + (size_t)(cb * 128) * 1024 + tid;
    for (int d = 0; d < 128; ++d) {
      const float* cp = cbase + (size_t)d * 1024;
      float x = xs[d];
#pragma unroll
      for (int vv = 0; vv < 4; ++vv) dot4[vv] = fmaf(x, cp[vv * 256], dot4[vv]);
    }
    float bd = FLT_MAX;
    int bi = 0;
#pragma unroll
    for (int vv = 0; vv < 4; ++vv) {
      int v = vv * 256 + tid;
      float d2 = xx - 2.f * dot4[vv] + c2[cb * 1024 + v];
      if (d2 < bd) { bd = d2; bi = v; }
    }
    rd[tid] = bd;
    ri[tid] = bi;
    __syncthreads();
    for (int s = 128; s > 0; s >>= 1) {
      if (tid < s) {
        float od = rd[tid + s];
        int oi = ri[tid + s];
        if (od < rd[tid] || (od == rd[tid] && oi < ri[tid])) { rd[tid] = od; ri[tid] = oi; }
      }
      __syncthreads();
    }
    if (tid == 0) {
      int b = mp / TFRP, t = mp % TFRP - 1;
      out[((size_t)b * 4 + cb) * TFR + t] = ri[0];
    }
  }
}

// ---------------- launch ----------------
extern "C" void kernel_launch(void* const* d_in, const int* in_sizes, int n_in,
                              void* d_out, int out_size, void* d_ws, size_t ws_size,
                              hipStream_t stream) {
  if (ws_size < WS_NEEDED) return;

  const float* wav = (const float*)d_in[0];
  const float* w1 = (const float*)d_in[1];
  const float* b1 = (const float*)d_in[2];
  const float* w2 = (const float*)d_in[3];
  const float* b2 = (const float*)d_in[4];
  const float* cbs = (const float*)d_in[5];
  int* out = (int*)d_out;

  char* W = (char*)d_ws;
  float* win = (float*)(W + OFF_WIN);
  float2* tw512 = (float2*)(W + OFF_TW512);
  float2* utw = (float2*)(W + OFF_UTW);
  float* c2mx = (float*)(W + OFF_C2MX);
  unsigned* cnt = (unsigned*)(W + OFF_CNT);
  float* melw = (float*)(W + OFF_MELW);
  int2* melsl = (int2*)(W + OFF_MELSL);
  float* wb1 = (float*)(W + OFF_WB1);
  u16* wbH2 = (u16*)(W + OFF_WBH2);
  u16* wbL2 = (u16*)(W + OFF_WBL2);
  float4* pb = (float4*)(W + OFF_PB);
  unsigned* list = (unsigned*)(W + OFF_LIST);
  float* wt2f = (float*)(W + OFF_WT2F);
  float* cbTf = (float*)(W + OFF_CBTF);
  float* c2 = (float*)(W + OFF_C2);
  u16* cbH = (u16*)(W + OFF_CBH);
  u16* cbL = (u16*)(W + OFF_CBL);
  float* x2 = (float*)(W + OFF_X2);
  float* hT = (float*)(W + OFF_HT);
  float* feT = (float*)(W + OFF_FET);
  float* lmT = (float*)(W + OFF_LMT);

  k_setup_tab<<<1, 1024, 0, stream>>>(win, tw512, utw);
  k_melw<<<1, 128, 0, stream>>>(melw, melsl);
  k_wt<<<(256 * 128 * 3 + 255) / 256, 256, 0, stream>>>(w1, wb1, 256, 128);
  k_wt2conv<<<1536, 256, 0, stream>>>(w2, wbH2, wbL2);
  k_c2<<<16, 256, 0, stream>>>(cbs, c2);
  k_c2mx<<<4, 256, 0, stream>>>(c2, c2mx, cnt);
  k_cbconv<<<512, 256, 0, stream>>>(cbs, cbH, cbL);

  k_logmel3<<<16 * 188, 256, 0, stream>>>(wav, win, tw512, utw, melw, melsl, lmT);
  k_zerocols<<<(128 * 32 + 255) / 256, 256, 0, stream>>>(lmT, 128);
  k_conv64<128, 256, 64, true><<<760, 256, 0, stream>>>(lmT, wb1, b1, hT);
  k_zerocols<<<(256 * 32 + 255) / 256, 256, 0, stream>>>(hT, 256);
  k_conv2m<<<760, 256, 0, stream>>>(hT, wbH2, wbL2, b2, feT);

  k_x2<<<dim3((PITCH2 + 255) / 256, 4), 256, 0, stream>>>(feT, x2);
  k_vqmfma<<<1520, 256, 0, stream>>>(feT, cbH, cbL, c2, pb);
  // feT dead now: build coalesced f32 tables in its region, then select + fix
  k_wt2f<<<1536, 256, 0, stream>>>(w2, wt2f);
  k_cbtf<<<2048, 256, 0, stream>>>(cbs, cbTf);
  k_vqsel<<<dim3((MROWS + 255) / 256, 4), 256, 0, stream>>>(pb, x2, c2mx, cnt, list, out);
  k_vqfix<<<2048, 256, 0, stream>>>(cnt, list, hT, wt2f, b2, cbTf, c2, out);
}